// Round 3
// baseline (363.403 us; speedup 1.0000x reference)
//
#include <hip/hip_runtime.h>

// Problem constants
#define B_    8
#define C_    128
#define H_    128
#define W_    128
#define NH    31              // (128-8)/4+1
#define NPB   (NH*NH)         // 961 patches per batch
#define NPAT  (B_*NPB)        // 7688
#define HW_   (H_*W_)
#define CHW_  (C_*HW_)
#define WS_BYTES ((size_t)NPAT * 8192 * 2)   // bf16 z per patch: 125,960,192 B

typedef float v4f __attribute__((ext_vector_type(4)));
typedef short v8s __attribute__((ext_vector_type(8)));

__device__ __forceinline__ unsigned short f2bf(float f) {
    unsigned int u = __builtin_bit_cast(unsigned int, f);
    u += 0x7FFFu + ((u >> 16) & 1u);   // RNE
    return (unsigned short)(u >> 16);
}
__device__ __forceinline__ unsigned int pack2bf(float lo, float hi) {
    return (unsigned int)f2bf(lo) | ((unsigned int)f2bf(hi) << 16);
}
__device__ __forceinline__ float bfs(unsigned short u) {
    return __builtin_bit_cast(float, ((unsigned int)u) << 16);
}

// ============================= PASS 1 =====================================
// v3: 256-thread / 4-wave blocks, one patch per block, 5 blocks/CU.
// ws layout is now [p][t(64)][c(128)] bf16.  Phase-2 A-tiles are remapped so
// tile A covers c in {0-3,8-11,16-19,24-27}+wb and tile B = +4; a lane then
// holds 8 CONSECUTIVE channels for its t -> one uint4 store per n2, 64B-dense
// per wave-instr.  The whole repack epilogue (sRep, B4, B5, 80 LDS instrs)
// is gone.  sVT swizzle key changed to (c&3)|(((c>>3)&1)<<2) so the phase-2
// read de-swizzle keeps the full 8-column spread (key(rowA) == l15&7).

__global__ __launch_bounds__(256, 5)
void patch_attn_ws(const float* __restrict__ q,
                   const float* __restrict__ k,
                   const float* __restrict__ v,
                   unsigned short* __restrict__ ws)
{
    __shared__ __align__(16) unsigned char lds[32768];
    unsigned short* sQ  = (unsigned short*)(lds);            // [64 t][128 c]
    unsigned short* sK  = (unsigned short*)(lds + 16384);    // [64 s][128 c]
    unsigned short* sVT = (unsigned short*)(lds);            // [128 c][64 s]
    unsigned short* sP  = (unsigned short*)(lds + 16384);    // [64 t][64 s]

    const int tid  = threadIdx.x;
    const int lane = tid & 63;
    const int l15  = lane & 15;
    const int quad = lane >> 4;
    const int wid  = tid >> 6;            // 0..3

    // batch-per-XCD swizzle
    const int p   = (blockIdx.x & 7) * NPB + (blockIdx.x >> 3);
    const int b   = p / NPB;
    const int rem = p - b * NPB;
    const int ph  = rem / NH;
    const int pw  = rem - ph * NH;
    const int h0  = ph * 4, w0 = pw * 4;
    const int baseB = b * CHW_;

    // ---- stage Q,K: adjacent-c pairs -> packed u32 LDS writes ----
    {
        float4 qa[4], qb[4], ka[4], kb[4];
        int c0A[4], tA[4];
        #pragma unroll
        for (int g = 0; g < 4; ++g) {
            int flat2 = tid + g * 256;        // 0..1023
            int jj = flat2 & 1;
            int i  = (flat2 >> 1) & 7;
            int cp = flat2 >> 4;              // 0..63
            int c0 = cp * 2;
            int off0 = baseB + c0 * HW_ + (h0 + i) * W_ + (w0 + jj * 4);
            qa[g] = *(const float4*)(q + off0);
            qb[g] = *(const float4*)(q + off0 + HW_);
            ka[g] = *(const float4*)(k + off0);
            kb[g] = *(const float4*)(k + off0 + HW_);
            c0A[g] = c0;
            tA[g]  = i * 8 + jj * 4;
        }
        #pragma unroll
        for (int g = 0; g < 4; ++g) {
            const float* fqa = (const float*)&qa[g];
            const float* fqb = (const float*)&qb[g];
            const float* fka = (const float*)&ka[g];
            const float* fkb = (const float*)&kb[g];
            int c0 = c0A[g];
            #pragma unroll
            for (int d = 0; d < 4; ++d) {
                int t = tA[g] + d;
                int chunk = (c0 >> 3) ^ (t & 15);
                int pos = t * 128 + chunk * 8 + (c0 & 7);
                *(unsigned int*)&sQ[pos] = pack2bf(fqa[d], fqb[d]);
                *(unsigned int*)&sK[pos] = pack2bf(fka[d], fkb[d]);
            }
        }
    }
    __syncthreads();   // B1

    // ---- phase 1: D[s][t] = K Q^T  (swapped operands) ----
    v4f acc0, acc1, acc2, acc3;
    acc0 = acc1 = acc2 = acc3 = (v4f){0.f, 0.f, 0.f, 0.f};
    const int rowT = wid * 16 + l15;
    #pragma unroll
    for (int kk = 0; kk < 4; ++kk) {
        int gph = (kk * 4 + quad) ^ l15;
        v8s bq = *(const v8s*)(&sQ[rowT * 128 + gph * 8]);
        v8s a0 = *(const v8s*)(&sK[( 0 + l15) * 128 + gph * 8]);
        v8s a1 = *(const v8s*)(&sK[(16 + l15) * 128 + gph * 8]);
        v8s a2 = *(const v8s*)(&sK[(32 + l15) * 128 + gph * 8]);
        v8s a3 = *(const v8s*)(&sK[(48 + l15) * 128 + gph * 8]);
        acc0 = __builtin_amdgcn_mfma_f32_16x16x32_bf16(a0, bq, acc0, 0, 0, 0);
        acc1 = __builtin_amdgcn_mfma_f32_16x16x32_bf16(a1, bq, acc1, 0, 0, 0);
        acc2 = __builtin_amdgcn_mfma_f32_16x16x32_bf16(a2, bq, acc2, 0, 0, 0);
        acc3 = __builtin_amdgcn_mfma_f32_16x16x32_bf16(a3, bq, acc3, 0, 0, 0);
    }

    // ---- issue V loads early (latency hidden under softmax) ----
    float4 rv[8];
    int cV[8], sV[8];
    #pragma unroll
    for (int g = 0; g < 8; ++g) {
        int flat4 = tid + g * 256;            // 0..2047
        int jj = flat4 & 1;
        int i  = (flat4 >> 1) & 7;
        int c  = flat4 >> 4;                  // 0..127
        rv[g] = *(const float4*)(v + baseB + c * HW_ + (h0 + i) * W_ + (w0 + jj * 4));
        cV[g] = c;
        sV[g] = i * 8 + jj * 4;
    }

    // ---- softmax over s (lane-local 16 values + quad exchange) ----
    const float scale = 0.08838834764831845f;
    float e0[4], e1[4], e2[4], e3[4];
    unsigned int pPk[8];                       // packed P, 4 m-tiles x uint2
    {
        float mx = -1e30f;
        #pragma unroll
        for (int r = 0; r < 4; ++r) {
            e0[r] = acc0[r] * scale; mx = fmaxf(mx, e0[r]);
            e1[r] = acc1[r] * scale; mx = fmaxf(mx, e1[r]);
            e2[r] = acc2[r] * scale; mx = fmaxf(mx, e2[r]);
            e3[r] = acc3[r] * scale; mx = fmaxf(mx, e3[r]);
        }
        mx = fmaxf(mx, __shfl_xor(mx, 16));
        mx = fmaxf(mx, __shfl_xor(mx, 32));
        float sum = 0.f;
        #pragma unroll
        for (int r = 0; r < 4; ++r) {
            e0[r] = __expf(e0[r] - mx); sum += e0[r];
            e1[r] = __expf(e1[r] - mx); sum += e1[r];
            e2[r] = __expf(e2[r] - mx); sum += e2[r];
            e3[r] = __expf(e3[r] - mx); sum += e3[r];
        }
        sum += __shfl_xor(sum, 16);
        sum += __shfl_xor(sum, 32);
        float inv = 1.0f / sum;
        pPk[0] = pack2bf(e0[0] * inv, e0[1] * inv);
        pPk[1] = pack2bf(e0[2] * inv, e0[3] * inv);
        pPk[2] = pack2bf(e1[0] * inv, e1[1] * inv);
        pPk[3] = pack2bf(e1[2] * inv, e1[3] * inv);
        pPk[4] = pack2bf(e2[0] * inv, e2[1] * inv);
        pPk[5] = pack2bf(e2[2] * inv, e2[3] * inv);
        pPk[6] = pack2bf(e3[0] * inv, e3[1] * inv);
        pPk[7] = pack2bf(e3[2] * inv, e3[3] * inv);
    }
    __syncthreads();   // B2: all phase-1 LDS reads done; sQ/sK reusable

    // ---- stage V -> sVT[c][s] (overlays sQ); swizzle key kV(c) ----
    #pragma unroll
    for (int g = 0; g < 8; ++g) {
        const float* fv = (const float*)&rv[g];
        int c = cV[g], s0 = sV[g];
        int kV = (c & 3) | (((c >> 3) & 1) << 2);
        unsigned int w0p = pack2bf(fv[0], fv[1]);
        unsigned int w1p = pack2bf(fv[2], fv[3]);
        int idx = c * 64 + ((((s0 >> 3) ^ kV) << 3) | (s0 & 7));
        uint2 val; val.x = w0p; val.y = w1p;
        *(uint2*)(&sVT[idx]) = val;
    }

    // ---- write P -> sP[t][s] (overlays sK head), normalized bf16 ----
    {
        const int t = rowT;
        const int qh = quad >> 1, ql = quad & 1;
        #pragma unroll
        for (int m = 0; m < 4; ++m) {
            int chunk = (m * 2 + qh) ^ (t & 7);
            uint2 val;
            val.x = pPk[m * 2];
            val.y = pPk[m * 2 + 1];
            *(uint2*)(&sP[t * 64 + chunk * 8 + ql * 4]) = val;
        }
    }
    __syncthreads();   // B3

    // ---- phase 2: Z[c][t] = V^T P^T ----
    // A-tile rows: tile A -> c = (m&3) + 8*(m>>2) + wb, tile B = +4.
    v4f z00, z01, z02, z03, z10, z11, z12, z13;
    z00 = z01 = z02 = z03 = (v4f){0.f, 0.f, 0.f, 0.f};
    z10 = z11 = z12 = z13 = (v4f){0.f, 0.f, 0.f, 0.f};
    const int wb = wid * 32;
    const int rA = wb + (l15 & 3) + ((l15 >> 2) << 3);
    #pragma unroll
    for (int kk = 0; kk < 2; ++kk) {
        int gph = (kk * 4 + quad) ^ (l15 & 7);
        v8s b0 = *(const v8s*)(&sP[( 0 + l15) * 64 + gph * 8]);
        v8s b1 = *(const v8s*)(&sP[(16 + l15) * 64 + gph * 8]);
        v8s b2 = *(const v8s*)(&sP[(32 + l15) * 64 + gph * 8]);
        v8s b3 = *(const v8s*)(&sP[(48 + l15) * 64 + gph * 8]);
        v8s aA = *(const v8s*)(&sVT[rA * 64 + gph * 8]);
        v8s aB = *(const v8s*)(&sVT[(rA + 4) * 64 + gph * 8]);
        z00 = __builtin_amdgcn_mfma_f32_16x16x32_bf16(aA, b0, z00, 0, 0, 0);
        z01 = __builtin_amdgcn_mfma_f32_16x16x32_bf16(aA, b1, z01, 0, 0, 0);
        z02 = __builtin_amdgcn_mfma_f32_16x16x32_bf16(aA, b2, z02, 0, 0, 0);
        z03 = __builtin_amdgcn_mfma_f32_16x16x32_bf16(aA, b3, z03, 0, 0, 0);
        z10 = __builtin_amdgcn_mfma_f32_16x16x32_bf16(aB, b0, z10, 0, 0, 0);
        z11 = __builtin_amdgcn_mfma_f32_16x16x32_bf16(aB, b1, z11, 0, 0, 0);
        z12 = __builtin_amdgcn_mfma_f32_16x16x32_bf16(aB, b2, z12, 0, 0, 0);
        z13 = __builtin_amdgcn_mfma_f32_16x16x32_bf16(aB, b3, z13, 0, 0, 0);
    }

    // ---- direct coalesced store: ws[p][t][c], uint4 = 8 consecutive c ----
    {
        unsigned short* wp = ws + (size_t)p * 8192 + wb + quad * 8;
        uint4 val;
        int t;
        t = 0 + l15;
        val.x = pack2bf(z00[0], z00[1]); val.y = pack2bf(z00[2], z00[3]);
        val.z = pack2bf(z10[0], z10[1]); val.w = pack2bf(z10[2], z10[3]);
        *(uint4*)(wp + t * 128) = val;
        t = 16 + l15;
        val.x = pack2bf(z01[0], z01[1]); val.y = pack2bf(z01[2], z01[3]);
        val.z = pack2bf(z11[0], z11[1]); val.w = pack2bf(z11[2], z11[3]);
        *(uint4*)(wp + t * 128) = val;
        t = 32 + l15;
        val.x = pack2bf(z02[0], z02[1]); val.y = pack2bf(z02[2], z02[3]);
        val.z = pack2bf(z12[0], z12[1]); val.w = pack2bf(z12[2], z12[3]);
        *(uint4*)(wp + t * 128) = val;
        t = 48 + l15;
        val.x = pack2bf(z03[0], z03[1]); val.y = pack2bf(z03[2], z03[3]);
        val.z = pack2bf(z13[0], z13[1]); val.w = pack2bf(z13[2], z13[3]);
        *(uint4*)(wp + t * 128) = val;
    }
}

// ============================= PASS 2 =====================================
// LDS-staged gather-merge for ws layout [p][t][c].
// Block = (b, hq, cg): out rows h = 4hq..4hq+3, all 128 w, 8 channels.
// sA holds t in [0,32) of patch-row hq; sB holds t in [32,64) of patch-row
// hq-1 (stored at local t-32).  Guard slots 0 and 32 are zeroed.
// Slot = [32 t][8 c] u16 + 8 pad = 264 u16 (528 B, != 0 mod 128 -> spread).

#define MSLOT 264                      // u16 per slot
#define MARR  (33 * MSLOT)             // u16 per array

__global__ __launch_bounds__(256, 4)
void merge_kernel(const unsigned short* __restrict__ ws,
                  float* __restrict__ out)
{
    __shared__ __align__(16) unsigned short sM[2 * MARR];   // 34848 B
    unsigned short* sA = sM;
    unsigned short* sB = sM + MARR;

    const int tid  = threadIdx.x;
    const int b    = blockIdx.x & 7;          // batch-per-XCD
    const int rest = blockIdx.x >> 3;         // 0..511
    const int hq   = rest >> 4;               // 0..31 : h = 4hq + hr
    const int cg   = rest & 15;

    // ---- zero guard slots (0 and 32 of each array) ----
    if (tid < 132) {
        int target = tid / 33;                // 0..3 : A0, A32, B0, B32
        int j      = tid - target * 33;
        unsigned short* base = ((target < 2) ? sA : sB)
                             + ((target & 1) ? 32 * MSLOT : 0);
        uint4 zz; zz.x = 0u; zz.y = 0u; zz.z = 0u; zz.w = 0u;
        *(uint4*)(base + j * 8) = zz;
    }

    // ---- stage: 2 halves x 31 pw x 32 t x 16 B (8 c) = 31744 B ----
    const int aValid = (hq <= 30);
    const int bValid = (hq >= 1);
    const int hqB = bValid ? (hq - 1) : 0;
    const size_t rowA = (size_t)(b * NPB + hq  * NH) * 8192;
    const size_t rowB = (size_t)(b * NPB + hqB * NH) * 8192;

    #pragma unroll
    for (int it = 0; it < 8; ++it) {
        int flat = tid + it * 256;            // 0..2047 ; 1984 used
        if (flat < 1984) {
            int half = (flat >= 992);
            int fl   = flat - (half ? 992 : 0);
            int pw   = fl >> 5;               // 0..30
            int t    = fl & 31;               // local t within half
            const unsigned short* src = ws
                + (half ? rowB : rowA)
                + (size_t)pw * 8192
                + (size_t)(half ? (t + 32) : t) * 128
                + cg * 8;
            int valid = half ? bValid : aValid;
            uint4 val;
            if (valid) {
                val = *(const uint4*)src;
            } else {
                val.x = 0u; val.y = 0u; val.z = 0u; val.w = 0u;
            }
            unsigned short* dst = (half ? sB : sA)
                + (pw + 1) * MSLOT + t * 8;
            *(uint4*)dst = val;
        }
    }
    __syncthreads();

    // ---- combine: out(4hq+hr, 4l+j, c) =
    //        A[l][hr*8+j] + A[l-1][hr*8+j+4] + B[l][hr*8+j] + B[l-1][hr*8+j+4]
    const int l    = tid & 31;                // w quad : w = 4l..4l+3
    const int csub = tid >> 5;                // 0..7
    const int c    = cg * 8 + csub;

    const int own  = (l + 1) * MSLOT + csub;
    const int left = l       * MSLOT + csub;

    float* op = out + b * CHW_ + c * HW_ + (hq * 4) * W_ + l * 4;
    #pragma unroll
    for (int hr = 0; hr < 4; ++hr) {
        float rr[4];
        #pragma unroll
        for (int j = 0; j < 4; ++j) {
            int tl = hr * 8 + j;
            float s = bfs(sA[own  + tl * 8])
                    + bfs(sA[left + (tl + 4) * 8])
                    + bfs(sB[own  + tl * 8])
                    + bfs(sB[left + (tl + 4) * 8]);
            rr[j] = s;
        }
        float4 r; r.x = rr[0]; r.y = rr[1]; r.z = rr[2]; r.w = rr[3];
        *(float4*)(op + hr * W_) = r;
    }
}

// ========================= FALLBACK (atomic) ==============================
// (does not use ws; unchanged)

__global__ __launch_bounds__(512, 6)
void patch_attn_atomic(const float* __restrict__ q,
                       const float* __restrict__ k,
                       const float* __restrict__ v,
                       float* __restrict__ out)
{
    __shared__ __align__(16) unsigned char lds[43264];
    unsigned short* sQ   = (unsigned short*)(lds);
    unsigned short* sK   = (unsigned short*)(lds + 16384);
    unsigned short* sVT  = (unsigned short*)(lds);
    unsigned short* sP   = (unsigned short*)(lds + 32768);
    float*          sRedM= (float*)(lds + 40960);
    float*          sRedL= (float*)(lds + 41984);
    float*          sInv = (float*)(lds + 43008);

    const int tid  = threadIdx.x;
    const int lane = tid & 63;
    const int wid  = tid >> 6;
    const int l15  = lane & 15;
    const int quad = lane >> 4;

    const int p   = (blockIdx.x & 7) * NPB + (blockIdx.x >> 3);
    const int b   = p / NPB;
    const int rem = p - b * NPB;
    const int ph  = rem / NH;
    const int pw  = rem - ph * NH;
    const int h0  = ph * 4, w0 = pw * 4;
    const int baseB = b * CHW_;

    float4 rq[4], rk[4], rv[4];
    int cA[4], tA[4];
    #pragma unroll
    for (int g = 0; g < 4; ++g) {
        int flat4 = tid + g * 512;
        int jj = flat4 & 1;
        int i  = (flat4 >> 1) & 7;
        int c  = flat4 >> 4;
        int off = baseB + c * HW_ + (h0 + i) * W_ + (w0 + jj * 4);
        rq[g] = *(const float4*)(q + off);
        rk[g] = *(const float4*)(k + off);
        rv[g] = *(const float4*)(v + off);
        cA[g] = c;
        tA[g] = i * 8 + jj * 4;
    }
    #pragma unroll
    for (int g = 0; g < 4; ++g) {
        const float* fq = (const float*)&rq[g];
        const float* fk = (const float*)&rk[g];
        int c = cA[g];
        #pragma unroll
        for (int d = 0; d < 4; ++d) {
            int t = tA[g] + d;
            int idx = t * 128 + ((((c >> 3) ^ (t & 15)) << 3) | (c & 7));
            sQ[idx] = f2bf(fq[d]);
            sK[idx] = f2bf(fk[d]);
        }
    }
    __syncthreads();

    const float scale = 0.08838834764831845f;
    const int nt  = wid & 3;
    const int mt0 = wid >> 2;

    v4f accT[2];
    #pragma unroll
    for (int ti = 0; ti < 2; ++ti) {
        int mt = mt0 + ti * 2;
        v4f acc = {0.f, 0.f, 0.f, 0.f};
        int rowA = mt * 16 + l15;
        int rowB = nt * 16 + l15;
        #pragma unroll
        for (int kk = 0; kk < 4; ++kk) {
            int gph = (kk * 4 + quad) ^ l15;
            v8s a  = *(const v8s*)(&sQ[rowA * 128 + gph * 8]);
            v8s bb = *(const v8s*)(&sK[rowB * 128 + gph * 8]);
            acc = __builtin_amdgcn_mfma_f32_16x16x32_bf16(a, bb, acc, 0, 0, 0);
        }
        #pragma unroll
        for (int r = 0; r < 4; ++r) acc[r] *= scale;
        accT[ti] = acc;
    }

    float4 mloc[2], eV[2];
    #pragma unroll
    for (int ti = 0; ti < 2; ++ti) {
        float4 m;
        #pragma unroll
        for (int r = 0; r < 4; ++r) m[r] = accT[ti][r];
        #pragma unroll
        for (int mask = 1; mask <= 8; mask <<= 1)
            #pragma unroll
            for (int r = 0; r < 4; ++r) m[r] = fmaxf(m[r], __shfl_xor(m[r], mask));
        float4 e, l;
        #pragma unroll
        for (int r = 0; r < 4; ++r) { e[r] = __expf(accT[ti][r] - m[r]); l[r] = e[r]; }
        #pragma unroll
        for (int mask = 1; mask <= 8; mask <<= 1)
            #pragma unroll
            for (int r = 0; r < 4; ++r) l[r] += __shfl_xor(l[r], mask);
        mloc[ti] = m; eV[ti] = e;
        if (l15 == 0) {
            int tb = (mt0 + ti * 2) * 16 + quad * 4;
            #pragma unroll
            for (int r = 0; r < 4; ++r) {
                sRedM[nt * 64 + tb + r] = m[r];
                sRedL[nt * 64 + tb + r] = l[r];
            }
        }
    }
    __syncthreads();

    #pragma unroll
    for (int g = 0; g < 4; ++g) {
        const float* fv = (const float*)&rv[g];
        unsigned short tmp[4];
        #pragma unroll
        for (int d = 0; d < 4; ++d) tmp[d] = f2bf(fv[d]);
        int c = cA[g], s0 = tA[g];
        int idx = c * 64 + ((((s0 >> 3) ^ (c & 7)) << 3) | (s0 & 7));
        *(uint2*)(&sVT[idx]) = *(const uint2*)tmp;
    }

    #pragma unroll
    for (int ti = 0; ti < 2; ++ti) {
        int tb = (mt0 + ti * 2) * 16 + quad * 4;
        float4 Mv[4], Lv[4];
        #pragma unroll
        for (int n2 = 0; n2 < 4; ++n2) {
            Mv[n2] = *(const float4*)(&sRedM[n2 * 64 + tb]);
            Lv[n2] = *(const float4*)(&sRedL[n2 * 64 + tb]);
        }
        float4 M = Mv[0], L;
        #pragma unroll
        for (int n2 = 1; n2 < 4; ++n2)
            #pragma unroll
            for (int r = 0; r < 4; ++r) M[r] = fmaxf(M[r], Mv[n2][r]);
        #pragma unroll
        for (int r = 0; r < 4; ++r) L[r] = 0.f;
        #pragma unroll
        for (int n2 = 0; n2 < 4; ++n2)
            #pragma unroll
            for (int r = 0; r < 4; ++r) L[r] += Lv[n2][r] * __expf(Mv[n2][r] - M[r]);
        #pragma unroll
        for (int r = 0; r < 4; ++r) {
            float pv = eV[ti][r] * __expf(mloc[ti][r] - M[r]);
            int t = tb + r;
            int s = nt * 16 + l15;
            sP[t * 64 + ((((s >> 3) ^ (t & 7)) << 3) | (s & 7))] = f2bf(pv);
        }
        if (nt == 0 && l15 == 0) {
            #pragma unroll
            for (int r = 0; r < 4; ++r) sInv[tb + r] = 1.0f / L[r];
        }
    }
    __syncthreads();

    v4f z[4];
    #pragma unroll
    for (int n2 = 0; n2 < 4; ++n2) z[n2] = (v4f){0.f, 0.f, 0.f, 0.f};
    const int crow = wid * 16 + l15;
    #pragma unroll
    for (int kk = 0; kk < 2; ++kk) {
        int gph = (kk * 4 + quad) ^ (l15 & 7);
        v8s a = *(const v8s*)(&sVT[crow * 64 + gph * 8]);
        #pragma unroll
        for (int n2 = 0; n2 < 4; ++n2) {
            int trow = n2 * 16 + l15;
            v8s bb = *(const v8s*)(&sP[trow * 64 + gph * 8]);
            z[n2] = __builtin_amdgcn_mfma_f32_16x16x32_bf16(a, bb, z[n2], 0, 0, 0);
        }
    }

    #pragma unroll
    for (int n2 = 0; n2 < 4; ++n2) {
        int t = n2 * 16 + l15;
        float inv = sInv[t];
        int base2 = baseB + (h0 + (t >> 3)) * W_ + (w0 + (t & 7));
        #pragma unroll
        for (int r = 0; r < 4; ++r) {
            int c = wid * 16 + quad * 4 + r;
            unsafeAtomicAdd(out + base2 + c * HW_, z[n2][r] * inv);
        }
    }
}

extern "C" void kernel_launch(void* const* d_in, const int* in_sizes, int n_in,
                              void* d_out, int out_size, void* d_ws, size_t ws_size,
                              hipStream_t stream) {
    const float* q = (const float*)d_in[0];
    const float* k = (const float*)d_in[1];
    const float* v = (const float*)d_in[2];
    float* out = (float*)d_out;

    if (ws_size >= WS_BYTES) {
        unsigned short* ws = (unsigned short*)d_ws;
        patch_attn_ws<<<NPAT, 256, 0, stream>>>(q, k, v, ws);
        merge_kernel<<<8 * 32 * 16, 256, 0, stream>>>(ws, out);
    } else {
        hipMemsetAsync(out, 0, (size_t)out_size * sizeof(float), stream);
        patch_attn_atomic<<<NPAT, 512, 0, stream>>>(q, k, v, out);
    }
}

// Round 4
// 356.542 us; speedup vs baseline: 1.0192x; 1.0192x over previous
//
#include <hip/hip_runtime.h>

// Problem constants
#define B_    8
#define C_    128
#define H_    128
#define W_    128
#define NH    31              // (128-8)/4+1
#define NPB   (NH*NH)         // 961 patches per batch
#define NPAT  (B_*NPB)        // 7688
#define HW_   (H_*W_)
#define CHW_  (C_*HW_)
#define WS_BYTES ((size_t)NPAT * 8192 * 2)   // bf16 z per patch: 125,960,192 B

typedef float v4f __attribute__((ext_vector_type(4)));
typedef short v8s __attribute__((ext_vector_type(8)));

__device__ __forceinline__ unsigned short f2bf(float f) {
    unsigned int u = __builtin_bit_cast(unsigned int, f);
    u += 0x7FFFu + ((u >> 16) & 1u);   // RNE
    return (unsigned short)(u >> 16);
}
__device__ __forceinline__ unsigned int pack2bf(float lo, float hi) {
    return (unsigned int)f2bf(lo) | ((unsigned int)f2bf(hi) << 16);
}
__device__ __forceinline__ float bflo(unsigned int d) {
    return __builtin_bit_cast(float, d << 16);
}
__device__ __forceinline__ float bfhi(unsigned int d) {
    return __builtin_bit_cast(float, d & 0xFFFF0000u);
}

// ============================= PASS 1 =====================================
// v3 (unchanged from round 3): 256-thread / 4-wave blocks, one patch per
// block.  ws layout [p][t(64)][c(128)] bf16; direct coalesced uint4 store
// from registers (no repack epilogue).

__global__ __launch_bounds__(256, 5)
void patch_attn_ws(const float* __restrict__ q,
                   const float* __restrict__ k,
                   const float* __restrict__ v,
                   unsigned short* __restrict__ ws)
{
    __shared__ __align__(16) unsigned char lds[32768];
    unsigned short* sQ  = (unsigned short*)(lds);            // [64 t][128 c]
    unsigned short* sK  = (unsigned short*)(lds + 16384);    // [64 s][128 c]
    unsigned short* sVT = (unsigned short*)(lds);            // [128 c][64 s]
    unsigned short* sP  = (unsigned short*)(lds + 16384);    // [64 t][64 s]

    const int tid  = threadIdx.x;
    const int lane = tid & 63;
    const int l15  = lane & 15;
    const int quad = lane >> 4;
    const int wid  = tid >> 6;            // 0..3

    // batch-per-XCD swizzle
    const int p   = (blockIdx.x & 7) * NPB + (blockIdx.x >> 3);
    const int b   = p / NPB;
    const int rem = p - b * NPB;
    const int ph  = rem / NH;
    const int pw  = rem - ph * NH;
    const int h0  = ph * 4, w0 = pw * 4;
    const int baseB = b * CHW_;

    // ---- stage Q,K: adjacent-c pairs -> packed u32 LDS writes ----
    {
        float4 qa[4], qb[4], ka[4], kb[4];
        int c0A[4], tA[4];
        #pragma unroll
        for (int g = 0; g < 4; ++g) {
            int flat2 = tid + g * 256;        // 0..1023
            int jj = flat2 & 1;
            int i  = (flat2 >> 1) & 7;
            int cp = flat2 >> 4;              // 0..63
            int c0 = cp * 2;
            int off0 = baseB + c0 * HW_ + (h0 + i) * W_ + (w0 + jj * 4);
            qa[g] = *(const float4*)(q + off0);
            qb[g] = *(const float4*)(q + off0 + HW_);
            ka[g] = *(const float4*)(k + off0);
            kb[g] = *(const float4*)(k + off0 + HW_);
            c0A[g] = c0;
            tA[g]  = i * 8 + jj * 4;
        }
        #pragma unroll
        for (int g = 0; g < 4; ++g) {
            const float* fqa = (const float*)&qa[g];
            const float* fqb = (const float*)&qb[g];
            const float* fka = (const float*)&ka[g];
            const float* fkb = (const float*)&kb[g];
            int c0 = c0A[g];
            #pragma unroll
            for (int d = 0; d < 4; ++d) {
                int t = tA[g] + d;
                int chunk = (c0 >> 3) ^ (t & 15);
                int pos = t * 128 + chunk * 8 + (c0 & 7);
                *(unsigned int*)&sQ[pos] = pack2bf(fqa[d], fqb[d]);
                *(unsigned int*)&sK[pos] = pack2bf(fka[d], fkb[d]);
            }
        }
    }
    __syncthreads();   // B1

    // ---- phase 1: D[s][t] = K Q^T  (swapped operands) ----
    v4f acc0, acc1, acc2, acc3;
    acc0 = acc1 = acc2 = acc3 = (v4f){0.f, 0.f, 0.f, 0.f};
    const int rowT = wid * 16 + l15;
    #pragma unroll
    for (int kk = 0; kk < 4; ++kk) {
        int gph = (kk * 4 + quad) ^ l15;
        v8s bq = *(const v8s*)(&sQ[rowT * 128 + gph * 8]);
        v8s a0 = *(const v8s*)(&sK[( 0 + l15) * 128 + gph * 8]);
        v8s a1 = *(const v8s*)(&sK[(16 + l15) * 128 + gph * 8]);
        v8s a2 = *(const v8s*)(&sK[(32 + l15) * 128 + gph * 8]);
        v8s a3 = *(const v8s*)(&sK[(48 + l15) * 128 + gph * 8]);
        acc0 = __builtin_amdgcn_mfma_f32_16x16x32_bf16(a0, bq, acc0, 0, 0, 0);
        acc1 = __builtin_amdgcn_mfma_f32_16x16x32_bf16(a1, bq, acc1, 0, 0, 0);
        acc2 = __builtin_amdgcn_mfma_f32_16x16x32_bf16(a2, bq, acc2, 0, 0, 0);
        acc3 = __builtin_amdgcn_mfma_f32_16x16x32_bf16(a3, bq, acc3, 0, 0, 0);
    }

    // ---- issue V loads early (latency hidden under softmax) ----
    float4 rv[8];
    int cV[8], sV[8];
    #pragma unroll
    for (int g = 0; g < 8; ++g) {
        int flat4 = tid + g * 256;            // 0..2047
        int jj = flat4 & 1;
        int i  = (flat4 >> 1) & 7;
        int c  = flat4 >> 4;                  // 0..127
        rv[g] = *(const float4*)(v + baseB + c * HW_ + (h0 + i) * W_ + (w0 + jj * 4));
        cV[g] = c;
        sV[g] = i * 8 + jj * 4;
    }

    // ---- softmax over s (lane-local 16 values + quad exchange) ----
    const float scale = 0.08838834764831845f;
    float e0[4], e1[4], e2[4], e3[4];
    unsigned int pPk[8];                       // packed P, 4 m-tiles x uint2
    {
        float mx = -1e30f;
        #pragma unroll
        for (int r = 0; r < 4; ++r) {
            e0[r] = acc0[r] * scale; mx = fmaxf(mx, e0[r]);
            e1[r] = acc1[r] * scale; mx = fmaxf(mx, e1[r]);
            e2[r] = acc2[r] * scale; mx = fmaxf(mx, e2[r]);
            e3[r] = acc3[r] * scale; mx = fmaxf(mx, e3[r]);
        }
        mx = fmaxf(mx, __shfl_xor(mx, 16));
        mx = fmaxf(mx, __shfl_xor(mx, 32));
        float sum = 0.f;
        #pragma unroll
        for (int r = 0; r < 4; ++r) {
            e0[r] = __expf(e0[r] - mx); sum += e0[r];
            e1[r] = __expf(e1[r] - mx); sum += e1[r];
            e2[r] = __expf(e2[r] - mx); sum += e2[r];
            e3[r] = __expf(e3[r] - mx); sum += e3[r];
        }
        sum += __shfl_xor(sum, 16);
        sum += __shfl_xor(sum, 32);
        float inv = 1.0f / sum;
        pPk[0] = pack2bf(e0[0] * inv, e0[1] * inv);
        pPk[1] = pack2bf(e0[2] * inv, e0[3] * inv);
        pPk[2] = pack2bf(e1[0] * inv, e1[1] * inv);
        pPk[3] = pack2bf(e1[2] * inv, e1[3] * inv);
        pPk[4] = pack2bf(e2[0] * inv, e2[1] * inv);
        pPk[5] = pack2bf(e2[2] * inv, e2[3] * inv);
        pPk[6] = pack2bf(e3[0] * inv, e3[1] * inv);
        pPk[7] = pack2bf(e3[2] * inv, e3[3] * inv);
    }
    __syncthreads();   // B2: all phase-1 LDS reads done; sQ/sK reusable

    // ---- stage V -> sVT[c][s] (overlays sQ); swizzle key kV(c) ----
    #pragma unroll
    for (int g = 0; g < 8; ++g) {
        const float* fv = (const float*)&rv[g];
        int c = cV[g], s0 = sV[g];
        int kV = (c & 3) | (((c >> 3) & 1) << 2);
        unsigned int w0p = pack2bf(fv[0], fv[1]);
        unsigned int w1p = pack2bf(fv[2], fv[3]);
        int idx = c * 64 + ((((s0 >> 3) ^ kV) << 3) | (s0 & 7));
        uint2 val; val.x = w0p; val.y = w1p;
        *(uint2*)(&sVT[idx]) = val;
    }

    // ---- write P -> sP[t][s] (overlays sK head), normalized bf16 ----
    {
        const int t = rowT;
        const int qh = quad >> 1, ql = quad & 1;
        #pragma unroll
        for (int m = 0; m < 4; ++m) {
            int chunk = (m * 2 + qh) ^ (t & 7);
            uint2 val;
            val.x = pPk[m * 2];
            val.y = pPk[m * 2 + 1];
            *(uint2*)(&sP[t * 64 + chunk * 8 + ql * 4]) = val;
        }
    }
    __syncthreads();   // B3

    // ---- phase 2: Z[c][t] = V^T P^T ----
    v4f z00, z01, z02, z03, z10, z11, z12, z13;
    z00 = z01 = z02 = z03 = (v4f){0.f, 0.f, 0.f, 0.f};
    z10 = z11 = z12 = z13 = (v4f){0.f, 0.f, 0.f, 0.f};
    const int wb = wid * 32;
    const int rA = wb + (l15 & 3) + ((l15 >> 2) << 3);
    #pragma unroll
    for (int kk = 0; kk < 2; ++kk) {
        int gph = (kk * 4 + quad) ^ (l15 & 7);
        v8s b0 = *(const v8s*)(&sP[( 0 + l15) * 64 + gph * 8]);
        v8s b1 = *(const v8s*)(&sP[(16 + l15) * 64 + gph * 8]);
        v8s b2 = *(const v8s*)(&sP[(32 + l15) * 64 + gph * 8]);
        v8s b3 = *(const v8s*)(&sP[(48 + l15) * 64 + gph * 8]);
        v8s aA = *(const v8s*)(&sVT[rA * 64 + gph * 8]);
        v8s aB = *(const v8s*)(&sVT[(rA + 4) * 64 + gph * 8]);
        z00 = __builtin_amdgcn_mfma_f32_16x16x32_bf16(aA, b0, z00, 0, 0, 0);
        z01 = __builtin_amdgcn_mfma_f32_16x16x32_bf16(aA, b1, z01, 0, 0, 0);
        z02 = __builtin_amdgcn_mfma_f32_16x16x32_bf16(aA, b2, z02, 0, 0, 0);
        z03 = __builtin_amdgcn_mfma_f32_16x16x32_bf16(aA, b3, z03, 0, 0, 0);
        z10 = __builtin_amdgcn_mfma_f32_16x16x32_bf16(aB, b0, z10, 0, 0, 0);
        z11 = __builtin_amdgcn_mfma_f32_16x16x32_bf16(aB, b1, z11, 0, 0, 0);
        z12 = __builtin_amdgcn_mfma_f32_16x16x32_bf16(aB, b2, z12, 0, 0, 0);
        z13 = __builtin_amdgcn_mfma_f32_16x16x32_bf16(aB, b3, z13, 0, 0, 0);
    }

    // ---- direct coalesced store: ws[p][t][c], uint4 = 8 consecutive c ----
    {
        unsigned short* wp = ws + (size_t)p * 8192 + wb + quad * 8;
        uint4 val;
        int t;
        t = 0 + l15;
        val.x = pack2bf(z00[0], z00[1]); val.y = pack2bf(z00[2], z00[3]);
        val.z = pack2bf(z10[0], z10[1]); val.w = pack2bf(z10[2], z10[3]);
        *(uint4*)(wp + t * 128) = val;
        t = 16 + l15;
        val.x = pack2bf(z01[0], z01[1]); val.y = pack2bf(z01[2], z01[3]);
        val.z = pack2bf(z11[0], z11[1]); val.w = pack2bf(z11[2], z11[3]);
        *(uint4*)(wp + t * 128) = val;
        t = 32 + l15;
        val.x = pack2bf(z02[0], z02[1]); val.y = pack2bf(z02[2], z02[3]);
        val.z = pack2bf(z12[0], z12[1]); val.w = pack2bf(z12[2], z12[3]);
        *(uint4*)(wp + t * 128) = val;
        t = 48 + l15;
        val.x = pack2bf(z03[0], z03[1]); val.y = pack2bf(z03[2], z03[3]);
        val.z = pack2bf(z13[0], z13[1]); val.w = pack2bf(z13[2], z13[3]);
        *(uint4*)(wp + t * 128) = val;
    }
}

// ============================= PASS 2 =====================================
// v4: dense contiguous merge for ws layout [p][t][c].
// Block = (b, hq, wseg): output rows h=4hq..4hq+3, w = wseg*16..+15, ALL c.
// Needs patches pw = wseg*4-1 .. wseg*4+3 (5 slots, guards zero-filled) from
// patch-row hq (A: first half, t 0..31 = contiguous 8KB) and patch-row hq-1
// (B: second half, t 32..63 = contiguous 8KB).  Staging is pure contiguous
// uint4 copies (1KB dense per wave-instr, 100% sector efficiency).
// Chunk XOR swizzle kc ^= ((slot&3)<<2)|(t&3) makes both staging writes and
// combine ds_read_b128 conflict-free (each 4-bank window gets exactly 8
// lanes = minimum).  LDS 80KB -> 2 blocks/CU.

#define SLOT_U16 4096                 // 8KB per patch-half slot

__global__ __launch_bounds__(256, 2)
void merge_kernel(const unsigned short* __restrict__ ws,
                  float* __restrict__ out)
{
    __shared__ __align__(16) unsigned short sM[10 * SLOT_U16];   // 80 KiB
    // slots 0..4 = A (row hq, t 0..31), slots 5..9 = B (row hq-1, t 32..63)

    const int tid  = threadIdx.x;
    const int b    = blockIdx.x & 7;          // batch-per-XCD
    const int rest = blockIdx.x >> 3;         // 0..255
    const int hq   = rest >> 3;               // 0..31
    const int wseg = rest & 7;                // 0..7
    const int l0   = wseg * 4;                // first own w-quad in block

    const int aValid = (hq <= 30);
    const int bValid = (hq >= 1);
    const size_t rowA = (size_t)(b * NPB + hq * NH) * 8192;
    const size_t rowB = (size_t)(b * NPB + (bValid ? hq - 1 : 0) * NH) * 8192;

    // ---- stage: 2 halves x 5 slots x 512 chunks x 16B = 80KB ----
    #pragma unroll
    for (int it = 0; it < 20; ++it) {
        int flat = tid + it * 256;            // 0..5119
        int half = (flat >= 2560);
        int r    = flat - (half ? 2560 : 0);
        int slot = r >> 9;                    // 0..4
        int ci   = r & 511;                   // chunk within 8KB half
        int t    = ci >> 4;                   // local t 0..31
        int kc   = ci & 15;                   // 16B chunk within c-line
        int pw   = l0 - 1 + slot;
        int valid = (pw >= 0) & (pw <= 30) & (half ? bValid : aValid);
        uint4 val; val.x = 0u; val.y = 0u; val.z = 0u; val.w = 0u;
        if (valid) {
            const unsigned short* src = ws + (half ? rowB : rowA)
                + (size_t)pw * 8192 + (half ? 4096 : 0) + ci * 8;
            val = *(const uint4*)src;
        }
        int kcs = kc ^ (((slot & 3) << 2) | (t & 3));
        unsigned short* dst = sM + (half * 5 + slot) * SLOT_U16 + t * 128 + kcs * 8;
        *(uint4*)dst = val;
    }
    __syncthreads();

    // ---- combine ----
    // thread: w16 = tid&15 (w = wseg*16+w16), kc = tid>>4 (c = kc*8..+7)
    const int w16  = tid & 15;
    const int kc   = tid >> 4;                // 0..15
    const int j    = w16 & 3;
    const int sOwn = (w16 >> 2) + 1;          // slot of own patch (pw = l)
    const int sLft = (w16 >> 2);              // slot of left patch (pw = l-1)
    const int c0   = kc * 8;

    const int gO = ((sOwn & 3) << 2) | j;     // swizzle keys
    const int gL = ((sLft & 3) << 2) | j;

    float* opBase = out + b * CHW_ + c0 * HW_ + (hq * 4) * W_ + wseg * 16 + w16;

    #pragma unroll
    for (int hr = 0; hr < 4; ++hr) {
        int t1 = hr * 8 + j;                  // own tw = j
        int t2 = t1 + 4;                      // left tw = j+4
        const unsigned short* aO = sM +  sOwn      * SLOT_U16 + t1 * 128 + (kc ^ gO) * 8;
        const unsigned short* aL = sM +  sLft      * SLOT_U16 + t2 * 128 + (kc ^ gL) * 8;
        const unsigned short* bO = sM + (5 + sOwn) * SLOT_U16 + t1 * 128 + (kc ^ gO) * 8;
        const unsigned short* bL = sM + (5 + sLft) * SLOT_U16 + t2 * 128 + (kc ^ gL) * 8;
        uint4 vaO = *(const uint4*)aO;
        uint4 vaL = *(const uint4*)aL;
        uint4 vbO = *(const uint4*)bO;
        uint4 vbL = *(const uint4*)bL;
        const unsigned int* uaO = (const unsigned int*)&vaO;
        const unsigned int* uaL = (const unsigned int*)&vaL;
        const unsigned int* ubO = (const unsigned int*)&vbO;
        const unsigned int* ubL = (const unsigned int*)&vbL;
        float* op = opBase + hr * W_;
        #pragma unroll
        for (int i = 0; i < 4; ++i) {
            float rlo = bflo(uaO[i]) + bflo(uaL[i]) + bflo(ubO[i]) + bflo(ubL[i]);
            float rhi = bfhi(uaO[i]) + bfhi(uaL[i]) + bfhi(ubO[i]) + bfhi(ubL[i]);
            op[(2 * i)     * HW_] = rlo;
            op[(2 * i + 1) * HW_] = rhi;
        }
    }
}

// ========================= FALLBACK (atomic) ==============================
// (does not use ws; unchanged)

__global__ __launch_bounds__(512, 6)
void patch_attn_atomic(const float* __restrict__ q,
                       const float* __restrict__ k,
                       const float* __restrict__ v,
                       float* __restrict__ out)
{
    __shared__ __align__(16) unsigned char lds[43264];
    unsigned short* sQ   = (unsigned short*)(lds);
    unsigned short* sK   = (unsigned short*)(lds + 16384);
    unsigned short* sVT  = (unsigned short*)(lds);
    unsigned short* sP   = (unsigned short*)(lds + 32768);
    float*          sRedM= (float*)(lds + 40960);
    float*          sRedL= (float*)(lds + 41984);
    float*          sInv = (float*)(lds + 43008);

    const int tid  = threadIdx.x;
    const int lane = tid & 63;
    const int wid  = tid >> 6;
    const int l15  = lane & 15;
    const int quad = lane >> 4;

    const int p   = (blockIdx.x & 7) * NPB + (blockIdx.x >> 3);
    const int b   = p / NPB;
    const int rem = p - b * NPB;
    const int ph  = rem / NH;
    const int pw  = rem - ph * NH;
    const int h0  = ph * 4, w0 = pw * 4;
    const int baseB = b * CHW_;

    float4 rq[4], rk[4], rv[4];
    int cA[4], tA[4];
    #pragma unroll
    for (int g = 0; g < 4; ++g) {
        int flat4 = tid + g * 512;
        int jj = flat4 & 1;
        int i  = (flat4 >> 1) & 7;
        int c  = flat4 >> 4;
        int off = baseB + c * HW_ + (h0 + i) * W_ + (w0 + jj * 4);
        rq[g] = *(const float4*)(q + off);
        rk[g] = *(const float4*)(k + off);
        rv[g] = *(const float4*)(v + off);
        cA[g] = c;
        tA[g] = i * 8 + jj * 4;
    }
    #pragma unroll
    for (int g = 0; g < 4; ++g) {
        const float* fq = (const float*)&rq[g];
        const float* fk = (const float*)&rk[g];
        int c = cA[g];
        #pragma unroll
        for (int d = 0; d < 4; ++d) {
            int t = tA[g] + d;
            int idx = t * 128 + ((((c >> 3) ^ (t & 15)) << 3) | (c & 7));
            sQ[idx] = f2bf(fq[d]);
            sK[idx] = f2bf(fk[d]);
        }
    }
    __syncthreads();

    const float scale = 0.08838834764831845f;
    const int nt  = wid & 3;
    const int mt0 = wid >> 2;

    v4f accT[2];
    #pragma unroll
    for (int ti = 0; ti < 2; ++ti) {
        int mt = mt0 + ti * 2;
        v4f acc = {0.f, 0.f, 0.f, 0.f};
        int rowA = mt * 16 + l15;
        int rowB = nt * 16 + l15;
        #pragma unroll
        for (int kk = 0; kk < 4; ++kk) {
            int gph = (kk * 4 + quad) ^ l15;
            v8s a  = *(const v8s*)(&sQ[rowA * 128 + gph * 8]);
            v8s bb = *(const v8s*)(&sK[rowB * 128 + gph * 8]);
            acc = __builtin_amdgcn_mfma_f32_16x16x32_bf16(a, bb, acc, 0, 0, 0);
        }
        #pragma unroll
        for (int r = 0; r < 4; ++r) acc[r] *= scale;
        accT[ti] = acc;
    }

    float4 mloc[2], eV[2];
    #pragma unroll
    for (int ti = 0; ti < 2; ++ti) {
        float4 m;
        #pragma unroll
        for (int r = 0; r < 4; ++r) m[r] = accT[ti][r];
        #pragma unroll
        for (int mask = 1; mask <= 8; mask <<= 1)
            #pragma unroll
            for (int r = 0; r < 4; ++r) m[r] = fmaxf(m[r], __shfl_xor(m[r], mask));
        float4 e, l;
        #pragma unroll
        for (int r = 0; r < 4; ++r) { e[r] = __expf(accT[ti][r] - m[r]); l[r] = e[r]; }
        #pragma unroll
        for (int mask = 1; mask <= 8; mask <<= 1)
            #pragma unroll
            for (int r = 0; r < 4; ++r) l[r] += __shfl_xor(l[r], mask);
        mloc[ti] = m; eV[ti] = e;
        if (l15 == 0) {
            int tb = (mt0 + ti * 2) * 16 + quad * 4;
            #pragma unroll
            for (int r = 0; r < 4; ++r) {
                sRedM[nt * 64 + tb + r] = m[r];
                sRedL[nt * 64 + tb + r] = l[r];
            }
        }
    }
    __syncthreads();

    #pragma unroll
    for (int g = 0; g < 4; ++g) {
        const float* fv = (const float*)&rv[g];
        unsigned short tmp[4];
        #pragma unroll
        for (int d = 0; d < 4; ++d) tmp[d] = f2bf(fv[d]);
        int c = cA[g], s0 = tA[g];
        int idx = c * 64 + ((((s0 >> 3) ^ (c & 7)) << 3) | (s0 & 7));
        *(uint2*)(&sVT[idx]) = *(const uint2*)tmp;
    }

    #pragma unroll
    for (int ti = 0; ti < 2; ++ti) {
        int tb = (mt0 + ti * 2) * 16 + quad * 4;
        float4 Mv[4], Lv[4];
        #pragma unroll
        for (int n2 = 0; n2 < 4; ++n2) {
            Mv[n2] = *(const float4*)(&sRedM[n2 * 64 + tb]);
            Lv[n2] = *(const float4*)(&sRedL[n2 * 64 + tb]);
        }
        float4 M = Mv[0], L;
        #pragma unroll
        for (int n2 = 1; n2 < 4; ++n2)
            #pragma unroll
            for (int r = 0; r < 4; ++r) M[r] = fmaxf(M[r], Mv[n2][r]);
        #pragma unroll
        for (int r = 0; r < 4; ++r) L[r] = 0.f;
        #pragma unroll
        for (int n2 = 0; n2 < 4; ++n2)
            #pragma unroll
            for (int r = 0; r < 4; ++r) L[r] += Lv[n2][r] * __expf(Mv[n2][r] - M[r]);
        #pragma unroll
        for (int r = 0; r < 4; ++r) {
            float pv = eV[ti][r] * __expf(mloc[ti][r] - M[r]);
            int t = tb + r;
            int s = nt * 16 + l15;
            sP[t * 64 + ((((s >> 3) ^ (t & 7)) << 3) | (s & 7))] = f2bf(pv);
        }
        if (nt == 0 && l15 == 0) {
            #pragma unroll
            for (int r = 0; r < 4; ++r) sInv[tb + r] = 1.0f / L[r];
        }
    }
    __syncthreads();

    v4f z[4];
    #pragma unroll
    for (int n2 = 0; n2 < 4; ++n2) z[n2] = (v4f){0.f, 0.f, 0.f, 0.f};
    const int crow = wid * 16 + l15;
    #pragma unroll
    for (int kk = 0; kk < 2; ++kk) {
        int gph = (kk * 4 + quad) ^ (l15 & 7);
        v8s a = *(const v8s*)(&sVT[crow * 64 + gph * 8]);
        #pragma unroll
        for (int n2 = 0; n2 < 4; ++n2) {
            int trow = n2 * 16 + l15;
            v8s bb = *(const v8s*)(&sP[trow * 64 + gph * 8]);
            z[n2] = __builtin_amdgcn_mfma_f32_16x16x32_bf16(a, bb, z[n2], 0, 0, 0);
        }
    }

    #pragma unroll
    for (int n2 = 0; n2 < 4; ++n2) {
        int t = n2 * 16 + l15;
        float inv = sInv[t];
        int base2 = baseB + (h0 + (t >> 3)) * W_ + (w0 + (t & 7));
        #pragma unroll
        for (int r = 0; r < 4; ++r) {
            int c = wid * 16 + quad * 4 + r;
            unsafeAtomicAdd(out + base2 + c * HW_, z[n2][r] * inv);
        }
    }
}

extern "C" void kernel_launch(void* const* d_in, const int* in_sizes, int n_in,
                              void* d_out, int out_size, void* d_ws, size_t ws_size,
                              hipStream_t stream) {
    const float* q = (const float*)d_in[0];
    const float* k = (const float*)d_in[1];
    const float* v = (const float*)d_in[2];
    float* out = (float*)d_out;

    if (ws_size >= WS_BYTES) {
        unsigned short* ws = (unsigned short*)d_ws;
        patch_attn_ws<<<NPAT, 256, 0, stream>>>(q, k, v, ws);
        merge_kernel<<<8 * 32 * 8, 256, 0, stream>>>(ws, out);
    } else {
        hipMemsetAsync(out, 0, (size_t)out_size * sizeof(float), stream);
        patch_attn_atomic<<<NPAT, 512, 0, stream>>>(q, k, v, out);
    }
}